// Round 21
// baseline (172.252 us; speedup 1.0000x reference)
//
#include <hip/hip_runtime.h>
#include <stdint.h>
#include <math.h>

#define NLEV 5
#define NIMG 16
#define NCLS 80
#define TOPK 1000
#define MTOT 5000
#define LPAD 1024
#define BNDCAP 4096
#define NBINS 288
#define BIN0 7846
#define OUTK 100
#define CHUNK 8192
#define NCHUNK 3216
#define CCAND 1024
#define ROWCAP 8192
#define CCAP 512

__device__ __constant__ int c_HW[NLEV]   = {15200, 3800, 950, 247, 70};
__device__ __constant__ int c_E[NLEV]    = {1216000, 304000, 76000, 19760, 5600};
__device__ __constant__ int c_cpr[NLEV]  = {149, 38, 10, 3, 1};          // 8192-chunks per (img,level) row
__device__ __constant__ int c_cbase[NLEV + 1] = {0, 2384, 2992, 3152, 3200, 3216};
// per-level gather-threshold bin: selection boundary B is ~{269,257,232,173,~60}
// on this data; GB chosen well below with 3x count margin. B < GB[l] -> exact fallback.
__device__ __constant__ int c_GB[NLEV]   = {256, 230, 179, 64, 0};

struct Params {
    const float* cls[NLEV];
    const float* reg[NLEV];
    const float* anc[NLEV];
    const int* imsize;
};

// ---- shared decode (must be used identically by k_selkr and k_merge) ----
__device__ inline void decode_entry(const Params& P, int img, int lvl, uint32_t idx,
                                    float bclip[4], int* cls_out, bool* nonempty) {
    int HW = c_HW[lvl];
    int loc = (int)idx / NCLS;
    int c = (int)idx - loc * NCLS;
    const float* a = P.anc[lvl] + 4 * loc;
    float a0 = a[0], a1 = a[1], a2 = a[2], a3 = a[3];
    const float* rg = P.reg[lvl] + (size_t)img * 4 * HW + loc;
    float d0 = rg[0], d1 = rg[HW], d2 = rg[2 * HW], d3 = rg[3 * HW];
    float w = a2 - a0 + 1.0f, h = a3 - a1 + 1.0f;
    float cx = a0 + 0.5f * w, cy = a1 + 0.5f * h;
    float dx = d0 / 10.0f, dy = d1 / 10.0f;
    const float SCALE_CLAMP = 4.135166556742356f;
    float dw = fminf(d2 / 5.0f, SCALE_CLAMP);
    float dh = fminf(d3 / 5.0f, SCALE_CLAMP);
    float pcx = dx * w + cx, pcy = dy * h + cy;
    float pw = (float)exp((double)dw) * w;
    float ph = (float)exp((double)dh) * h;
    float x1 = pcx - 0.5f * (pw - 1.0f), y1 = pcy - 0.5f * (ph - 1.0f);
    float x2 = pcx + 0.5f * (pw - 1.0f), y2 = pcy + 0.5f * (ph - 1.0f);
    float Hs = (float)P.imsize[img * 2 + 0];
    float Ws = (float)P.imsize[img * 2 + 1];
    float x1c = fminf(fmaxf(x1, 0.0f), Ws);
    float y1c = fminf(fmaxf(y1, 0.0f), Hs);
    float x2c = fminf(fmaxf(x2, 0.0f), Ws);
    float y2c = fminf(fmaxf(y2, 0.0f), Hs);
    bclip[0] = x1c; bclip[1] = y1c; bclip[2] = x2c; bclip[3] = y2c;
    *cls_out = c;
    *nonempty = ((x2c - x1c) > 0.0f) && ((y2c - y1c) > 0.0f);
}

__device__ inline float sigmoid_f(float x) {
    return (float)(1.0 / (1.0 + exp(-(double)x)));
}

__device__ inline uint32_t f2o(float f) {
    uint32_t b = __float_as_uint(f);
    return (b & 0x80000000u) ? ~b : (b | 0x80000000u);
}
__device__ inline float o2f(uint32_t o) {
    uint32_t b = (o & 0x80000000u) ? (o & 0x7FFFFFFFu) : ~o;
    return __uint_as_float(b);
}

__device__ inline void chunk_map(int bid, int* lvl, int* img, int* start, int* end) {
    int l = 0;
#pragma unroll
    for (int q = 1; q < NLEV; q++) if (bid >= c_cbase[q]) l = q;
    int r = bid - c_cbase[l];
    int cpr = c_cpr[l];
    int im = r / cpr;
    int ch = r - im * cpr;
    int E = c_E[l];
    int st = ch * CHUNK;
    *lvl = l; *img = im; *start = st; *end = min(st + CHUNK, E);
}

// ---- K0: thresholds T[b] + zero hist + zero rowCnt/fbflag/histBad ----
__global__ __launch_bounds__(320) void k_thr(float* T, uint32_t* hist, uint32_t* cnts) {
    int b = blockIdx.x;
    int t = threadIdx.x;
    if (t < NBINS) hist[b * NBINS + t] = 0;
    if (b == 1 && t < 240) cnts[t] = 0;     // rowCnt[80] + fbflag[80] + histBad[80]
    if (b == 0 && t < NBINS) {
        uint32_t lo = f2o(-4.0f), hi = f2o(20.0f);
        while (hi - lo > 1u) {
            uint32_t mid = lo + ((hi - lo) >> 1);
            float xm = o2f(mid);
            float s = sigmoid_f(xm);
            bool pass = (s > 0.05f) && (((int)(__float_as_uint(s) >> 17) - BIN0) >= t);
            if (pass) hi = mid; else lo = mid;
        }
        float xr = o2f(hi);
        float sv = sigmoid_f(xr);
        bool ok = (sv > 0.05f) && (((int)(__float_as_uint(sv) >> 17) - BIN0) >= t);
        T[t] = ok ? xr : __uint_as_float(0x7F800000u);
    }
}

// ---- K1: single 104MB stream via global_load_lds DMA staging (no dest
// VGPRs -> loads cannot be sunk; 8 fire-and-forget 1KB DMAs per wave).
// Then push-only compare loop over LDS; bin/idx work in compact post-pass. ----
__global__ __launch_bounds__(256) void k_hist(Params P, const float* __restrict__ T,
                                              uint32_t* __restrict__ hist,
                                              uint64_t* __restrict__ rowCand,
                                              uint32_t* __restrict__ rowCnt,
                                              uint32_t* __restrict__ fbflag,
                                              uint32_t* __restrict__ histBad) {
    __shared__ float4 lbuf[2048];      // 32 KB chunk stage
    __shared__ uint32_t lh[NBINS];
    __shared__ float sT[NBINS];
    __shared__ uint64_t cand[CCAND];
    __shared__ uint32_t ccnt, wbase;
    int l, img, start, end;
    chunk_map(blockIdx.x, &l, &img, &start, &end);
    for (int b = threadIdx.x; b < NBINS; b += 256) { lh[b] = 0; sT[b] = T[b]; }
    if (threadIdx.x == 0) ccnt = 0;
    float gthr_pre = T[c_GB[l]];
    int HW = c_HW[l];
    int row = l * NIMG + img;
    const float4* __restrict__ p = (const float4*)(P.cls[l] + (size_t)img * c_E[l] + start);
    int n4 = (end - start) >> 2;
    // tail sentinels (slots the masked DMA lanes won't touch)
    for (int f = n4 + (int)threadIdx.x; f < 2048; f += 256)
        lbuf[f] = make_float4(-1e30f, -1e30f, -1e30f, -1e30f);
    // ---- DMA staging: wave-uniform LDS base + lane*16, masked tail lanes ----
    int lane = threadIdx.x & 63;
    int wave = threadIdx.x >> 6;
#pragma unroll
    for (int u = 0; u < 8; u++) {
        int fbase = (wave * 8 + u) * 64;
        int f = fbase + lane;
        if (f < n4) {
            __builtin_amdgcn_global_load_lds(
                (const __attribute__((address_space(1))) void*)(p + f),
                (__attribute__((address_space(3))) void*)&lbuf[fbase], 16, 0, 0);
        }
    }
    __syncthreads();   // drains vmcnt (DMA) + lgkmcnt (sentinel ds_writes)
    float gthr = gthr_pre;
    // ---- push-only compare loop over LDS ----
#pragma unroll
    for (int u = 0; u < 8; u++) {
        float4 x4 = lbuf[u * 256 + threadIdx.x];
        float xs[4] = {x4.x, x4.y, x4.z, x4.w};
#pragma unroll
        for (int k = 0; k < 4; k++) {
            float xv = xs[k];
            if (xv >= gthr) {                     // push-only: bits + chunk pos
                uint32_t lp = atomicAdd(&ccnt, 1u);
                if (lp < CCAND) {
                    uint32_t pos = (uint32_t)((u * 256 + threadIdx.x) * 4 + k);
                    cand[lp] = ((uint64_t)__float_as_uint(xv) << 32) | pos;
                }
            }
        }
    }
    __syncthreads();
    uint32_t cc = ccnt;
    uint32_t n = min(cc, (uint32_t)CCAND);
    if (threadIdx.x == 0) {
        wbase = atomicAdd(&rowCnt[row], n);
        if (cc > CCAND) { atomicOr(&fbflag[row], 1u); atomicOr(&histBad[row], 1u); }
        else if (wbase + n > ROWCAP) atomicOr(&fbflag[row], 1u);
    }
    __syncthreads();
    // ---- compact post-pass: exact bin + idx + rowCand write (~94 items) ----
    for (uint32_t i = threadIdx.x; i < n; i += 256) {
        uint64_t rec = cand[i];
        float xv = __uint_as_float((uint32_t)(rec >> 32));
        int pos = (int)(rec & 0xFFFFu);
        float se = 1.0f / (1.0f + __expf(-xv));   // estimator only
        int b = (int)(__float_as_uint(se) >> 17) - BIN0;
        b = min(max(b, 0), NBINS - 1);
        while (b > 0 && xv < sT[b]) b--;          // exact fix-up:
        while (b + 1 < NBINS && xv >= sT[b + 1]) b++;  // T[b]<=x<T[b+1]
        atomicAdd(&lh[b], 1u);
        int q2 = start + pos;                     // c*HW + p layout
        int c = q2 / HW;
        int pidx = q2 - c * HW;
        uint32_t idx = (uint32_t)(pidx * NCLS + c);
        uint32_t gpos = wbase + i;
        if (gpos < ROWCAP)
            rowCand[(size_t)row * ROWCAP + gpos] = ((uint64_t)__float_as_uint(xv) << 32) | idx;
    }
    __syncthreads();
    for (int b = threadIdx.x; b < NBINS; b += 256) {
        uint32_t c = lh[b];
        if (c) atomicAdd(&hist[row * NBINS + b], c);
    }
}

// ---- K2 (fused scan + fallback-hist): scan bins 287..GB[l]; if boundary
// not found or hist untrusted, recompute exact full-range hist in-kernel
// (direct row scan; exact, dormant on bench data) and rescan. ----
__global__ __launch_bounds__(1024) void k_scanfb(Params P, const float* T,
                                                 const uint32_t* hist, int* sel,
                                                 uint32_t* fbflag, const uint32_t* histBad) {
    __shared__ uint32_t lh[NBINS];
    __shared__ int s_bad;
    int row = blockIdx.x;
    if (threadIdx.x < NBINS) lh[threadIdx.x] = hist[row * NBINS + threadIdx.x];
    if (threadIdx.x == 0) s_bad = 0;
    __syncthreads();
    int l = row / NIMG;
    if (threadIdx.x == 0) {
        int GBl = c_GB[l];
        int cum = 0, B = -3, need = 0, cab = 0;
        if (histBad[row] == 0) {
            for (int b = NBINS - 1; b >= GBl; b--) {
                int c = (int)lh[b];
                if (cum + c >= TOPK) { B = b; cab = cum; need = TOPK - cum; break; }
                cum += c;
            }
        }
        if (B == -3) {
            s_bad = 1;
            fbflag[row] = 1;
        } else {
            sel[row * 4 + 0] = B;
            sel[row * 4 + 1] = cab;
            sel[row * 4 + 2] = need;
            sel[row * 4 + 3] = cum;
        }
    }
    __syncthreads();
    if (!s_bad) return;
    int img = row - l * NIMG;
    int E = c_E[l];
    float t0 = T[0];
    for (int b = threadIdx.x; b < NBINS; b += 1024) lh[b] = 0;
    __syncthreads();
    const float* base = P.cls[l] + (size_t)img * E;
    for (int e = threadIdx.x; e < E; e += 1024) {
        float xv = base[e];
        if (xv >= t0) {
            float sc = sigmoid_f(xv);
            int b = (int)(__float_as_uint(sc) >> 17) - BIN0;
            b = min(max(b, 0), NBINS - 1);
            atomicAdd(&lh[b], 1u);
        }
    }
    __syncthreads();
    if (threadIdx.x == 0) {
        int cum = 0, B = -1, need = 0, cab = 0;
        for (int b = NBINS - 1; b >= 0; b--) {
            int c = (int)lh[b];
            if (cum + c >= TOPK) { B = b; cab = cum; need = TOPK - cum; break; }
            cum += c;
        }
        if (B < 0) { cab = cum; need = 0; }
        sel[row * 4 + 0] = B;
        sel[row * 4 + 1] = cab;
        sel[row * 4 + 2] = need;
        sel[row * 4 + 3] = cum;
    }
}

// ---- K3 (selsort + keys + rsort): records carry LOGIT bits; bin classes
//      via T-compares (exact: bin>=b <=> x>=T[b]); score bits computed only
//      for boundary sort + selected key slots. Fallback = direct row scan. ----
__global__ __launch_bounds__(1024) void k_selkr(Params P, const int* sel, const float* T,
                                                const uint64_t* rowCand, const uint32_t* rowCnt,
                                                const uint32_t* fbflag, uint64_t* keys) {
    __shared__ uint64_t smain[1024];
    __shared__ uint64_t sbnd[BNDCAP];
    __shared__ uint64_t kk[LPAD];
    __shared__ uint32_t cnt0, cnt1;
    int blk = blockIdx.x;              // keys layout [img][lvl][1024]
    int img = blk / NLEV, lvl = blk - img * NLEV;
    int row = lvl * NIMG + img;
    int B = sel[row * 4 + 0], cab = sel[row * 4 + 1];
    int need = sel[row * 4 + 2], cum = sel[row * 4 + 3];
    float xt = T[max(B, 0)];                       // == T[B] when B>=0
    float tB1 = T[min(B + 1, NBINS - 1)];          // bin>B  <=> x >= T[B+1]
    int HW = c_HW[lvl];
    int E = c_E[lvl];
    if (threadIdx.x == 0) { cnt0 = 0; cnt1 = 0; }
    __syncthreads();
    uint32_t rcnt = rowCnt[row];
    bool fb = (fbflag[row] != 0) || (rcnt > ROWCAP);
    if (!fb) {
        const uint64_t* rc = rowCand + (size_t)row * ROWCAP;
        int cntr = (int)rcnt;
        for (int i = threadIdx.x; i < cntr; i += 1024) {
            uint64_t rec = rc[i];
            float x = __uint_as_float((uint32_t)(rec >> 32));
            if (x >= tB1) {
                uint32_t lp = atomicAdd(&cnt0, 1u);
                if (lp < 1024) smain[lp] = rec;   // cab<=999 -> never overflows
            } else if (x >= xt) {
                uint32_t lp = atomicAdd(&cnt1, 1u);
                if (lp < BNDCAP) sbnd[lp] = rec;
            }
        }
    } else {
        // ---- exact fallback: direct full-row scan (slow path) ----
        const float* base = P.cls[lvl] + (size_t)img * E;
        for (int e = threadIdx.x; e < E; e += 1024) {
            float xv = base[e];
            if (xv >= xt) {
                int c = e / HW;
                int pidx = e - c * HW;
                uint32_t idx = (uint32_t)(pidx * NCLS + c);
                uint64_t rec = ((uint64_t)__float_as_uint(xv) << 32) | idx;
                if (xv >= tB1) {
                    uint32_t lp = atomicAdd(&cnt0, 1u);
                    if (lp < 1024) smain[lp] = rec;
                } else {
                    uint32_t lp = atomicAdd(&cnt1, 1u);
                    if (lp < BNDCAP) sbnd[lp] = rec;
                }
            }
        }
    }
    __syncthreads();
    // ---- boundary: convert logit->exact score bits, sort (desc, idx asc) ----
    int take = 0;
    int cnt = min((int)cnt1, BNDCAP);
    if (need > 0) {
        for (int i = threadIdx.x; i < cnt; i += 1024) {
            uint64_t r = sbnd[i];
            float x = __uint_as_float((uint32_t)(r >> 32));
            uint32_t sb = __float_as_uint(sigmoid_f(x));
            sbnd[i] = ((uint64_t)(uint32_t)(~sb) << 32) | (uint32_t)r;
        }
        __syncthreads();
        int N = 64; while (N < cnt) N <<= 1;
        for (int i = threadIdx.x; i < N; i += 1024) {
            if (i >= cnt) sbnd[i] = ~0ULL;
        }
        __syncthreads();
        for (int k = 2; k <= N; k <<= 1) {
            for (int j = k >> 1; j > 0; j >>= 1) {
                for (int i = threadIdx.x; i < N; i += 1024) {
                    int ixj = i ^ j;
                    if (ixj > i) {
                        uint64_t A = sbnd[i], Bv = sbnd[ixj];
                        bool up = ((i & k) == 0);
                        if (up ? (A > Bv) : (A < Bv)) { sbnd[i] = Bv; sbnd[ixj] = A; }
                    }
                }
                __syncthreads();
            }
        }
        take = min(need, cnt);
    }
    int nmain = min((int)cnt0, 1024);
    int filled = (B < 0) ? cum : (cab + take);
    // ---- build 1024 keys (exact score bits via sigmoid_f), sort, store ----
    for (int slot = threadIdx.x; slot < LPAD; slot += 1024) {
        uint64_t key;
        if (slot >= TOPK) key = ~0ULL;
        else {
            uint32_t bits = 0, idx = 0;
            if (slot < filled) {
                if (slot < cab || B < 0) {
                    if (slot < nmain) {
                        uint64_t r = smain[slot];
                        float x = __uint_as_float((uint32_t)(r >> 32));
                        bits = __float_as_uint(sigmoid_f(x));
                        idx = (uint32_t)r;
                    }
                } else {
                    uint64_t wv = sbnd[slot - cab];
                    bits = ~((uint32_t)(wv >> 32));
                    idx = (uint32_t)wv;
                }
            }
            uint32_t be = 0;
            if (bits != 0) {
                float bc[4]; int cc; bool ne;
                decode_entry(P, img, lvl, idx, bc, &cc, &ne);
                if (ne) be = bits;
            }
            key = ((uint64_t)(uint32_t)(~be) << 24) | ((uint64_t)lvl << 21) | (uint64_t)idx;
        }
        kk[slot] = key;
    }
    __syncthreads();
    for (int k = 2; k <= LPAD; k <<= 1) {
        for (int j = k >> 1; j > 0; j >>= 1) {
            for (int i = threadIdx.x; i < LPAD; i += 1024) {
                int ixj = i ^ j;
                if (ixj > i) {
                    uint64_t A = kk[i], Bv = kk[ixj];
                    bool up = ((i & k) == 0);
                    if (up ? (A > Bv) : (A < Bv)) { kk[i] = Bv; kk[ixj] = A; }
                }
            }
            __syncthreads();
        }
    }
    uint64_t* g = keys + (size_t)blk * LPAD;
    for (int i = threadIdx.x; i < LPAD; i += 1024) g[i] = kk[i];
}

// ---- K4 (fused merge+prep): 4 blocks/image ----
__global__ __launch_bounds__(1024) void k_merge(Params P, const uint64_t* keys,
                                                float4* boff, float* area, float4* bclip,
                                                float* scs, int* clss,
                                                uint8_t* keepB, uint8_t* clsB) {
    __shared__ uint64_t sl[NLEV * LPAD];   // 40 KB
    int img = blockIdx.x >> 2;
    int part = blockIdx.x & 3;
    const uint64_t* g = keys + (size_t)img * NLEV * LPAD;
    for (int i = threadIdx.x; i < NLEV * LPAD; i += 1024) sl[i] = g[i];
    __syncthreads();
    const int gb = img * MTOT;
    int e0 = part * (NLEV * LPAD / 4);
    int e1 = e0 + (NLEV * LPAD / 4);
    for (int e = e0 + threadIdx.x; e < e1; e += 1024) {
        int l = e >> 10, i = e & (LPAD - 1);
        if (i >= TOPK) continue;
        uint64_t K = sl[e];
        int rank = i;
#pragma unroll
        for (int l2 = 0; l2 < NLEV; l2++) {
            if (l2 == l) continue;
            const uint64_t* s2 = &sl[l2 << 10];
            int lo = 0, hi = TOPK;
            while (lo < hi) {
                int mid = (lo + hi) >> 1;
                if (s2[mid] < K) lo = mid + 1; else hi = mid;
            }
            rank += lo;
        }
        uint32_t bits = ~((uint32_t)(K >> 24));
        int lvl = (int)((K >> 21) & 7);
        uint32_t idx = (uint32_t)(K & 0x1FFFFF);
        float bc[4]; int cc; bool ne;
        decode_entry(P, img, lvl, idx, bc, &cc, &ne);
        float sc = 0.0f;
        if (bits != 0) {
            float s = __uint_as_float(bits);
            sc = sqrtf(fmaxf(s, 1e-12f));
        }
        float off = (float)cc * 2000.0f;
        float b0 = bc[0] + off, b1 = bc[1] + off, b2 = bc[2] + off, b3 = bc[3] + off;
        int t = gb + rank;
        boff[t] = make_float4(b0, b1, b2, b3);
        area[t] = (b2 - b0) * (b3 - b1);
        bclip[t] = make_float4(bc[0], bc[1], bc[2], bc[3]);
        scs[t] = sc;
        clss[t] = cc;
        keepB[t] = 0;
        clsB[t] = (sc != 0.0f) ? (uint8_t)cc : (uint8_t)0xFF;
    }
}

// ---- K5: per-(img,class) greedy NMS; byte-map bucket build ----
__global__ __launch_bounds__(64) void k_cnms(const float4* boff, const float* area,
                                             const uint8_t* clsB, uint8_t* keepB) {
    __shared__ float sx1[CCAP], sy1[CCAP], sx2[CCAP], sy2[CCAP], sar[CCAP];
    __shared__ uint16_t ranks[CCAP];
    int img = blockIdx.x / NCLS;
    int cls = blockIdx.x - img * NCLS;
    int lane = threadIdx.x;
    const int gb = img * MTOT;

    int n = 0;
    const uchar4* cp = (const uchar4*)(clsB + gb);
    for (int base = 0; base < 1250; base += 64) {
        int q = base + lane;
        uchar4 cv = (q < 1250) ? cp[q] : make_uchar4(255, 255, 255, 255);
#pragma unroll
        for (int b = 0; b < 4; b++) {
            int cb = (b == 0) ? cv.x : (b == 1) ? cv.y : (b == 2) ? cv.z : cv.w;
            bool pred = (cb == cls);
            uint64_t mask = __ballot(pred);
            int pos = n + (int)__popcll(mask & ((1ULL << lane) - 1ULL));
            if (pred && pos < CCAP) ranks[pos] = (uint16_t)(q * 4 + b);
            n += (int)__popcll(mask);
        }
    }
    n = min(n, CCAP);
    __syncthreads();
    if (n == 0) return;

    for (int i = lane; i < n; i += 64) {
        int t = ranks[i];
        float4 b = boff[gb + t];
        sx1[i] = b.x; sy1[i] = b.y; sx2[i] = b.z; sy2[i] = b.w;
        sar[i] = area[gb + t];
    }
    __syncthreads();

    uint64_t m[CCAP / 64];
#pragma unroll
    for (int c = 0; c < CCAP / 64; c++) m[c] = 0ULL;
#pragma unroll
    for (int c = 0; c < CCAP / 64; c++) {
        if (c * 64 >= n) break;
        for (int ii = 0; ii < 64; ii++) {
            int i = c * 64 + ii;
            if (i >= n) break;
            if ((m[c] >> ii) & 1ULL) continue;
            float bx1 = sx1[i], by1 = sy1[i], bx2 = sx2[i], by2 = sy2[i], bai = sar[i];
            if (lane == 0) keepB[gb + ranks[i]] = 1;
#pragma unroll
            for (int c2 = 0; c2 < CCAP / 64; c2++) {
                if (c2 < c) continue;
                if (c2 * 64 >= n) break;
                int j = c2 * 64 + lane;
                float xx1 = fmaxf(bx1, sx1[j]), yy1 = fmaxf(by1, sy1[j]);
                float xx2 = fminf(bx2, sx2[j]), yy2 = fminf(by2, sy2[j]);
                float inter = fmaxf(xx2 - xx1, 0.0f) * fmaxf(yy2 - yy1, 0.0f);
                float iou = inter / (bai + sar[j] - inter + 1e-9f);
                bool pr = (j > i) && (j < n) && (iou > 0.6f);
                m[c2] |= __ballot(pr);
            }
        }
    }
}

// ---- K6: per-image output: first 100 kept (rank order) + filler ----
__global__ __launch_bounds__(64) void k_out(const float4* bclip, const float* scs,
                                            const int* clss, const uint8_t* keepB, float* out) {
    __shared__ int keptIdx[OUTK];
    int img = blockIdx.x;
    int lane = threadIdx.x;
    const int gb = img * MTOT;
    int kc = 0;
    for (int base = 0; base < MTOT && kc < OUTK; base += 64) {
        int t = base + lane;
        bool pred = (t < MTOT) && (keepB[gb + t] != 0);
        uint64_t mask = __ballot(pred);
        int pos = kc + (int)__popcll(mask & ((1ULL << lane) - 1ULL));
        if (pred && pos < OUTK) keptIdx[pos] = t;
        kc = min(kc + (int)__popcll(mask), OUTK);
    }
    for (int base = 0; base < MTOT && kc < OUTK; base += 64) {
        int t = base + lane;
        bool pred = (t < MTOT) && (keepB[gb + t] == 0);
        uint64_t mask = __ballot(pred);
        int pos = kc + (int)__popcll(mask & ((1ULL << lane) - 1ULL));
        if (pred && pos < OUTK) keptIdx[pos] = t | (1 << 30);
        kc = min(kc + (int)__popcll(mask), OUTK);
    }
    __syncthreads();
    for (int t = lane; t < OUTK; t += 64) {
        int ke = keptIdx[t];
        bool fil = (ke >> 30) & 1;
        int e = ke & 0x3FFFFFFF;
        float4 b = bclip[gb + e];
        out[((size_t)img * OUTK + t) * 4 + 0] = b.x;
        out[((size_t)img * OUTK + t) * 4 + 1] = b.y;
        out[((size_t)img * OUTK + t) * 4 + 2] = b.z;
        out[((size_t)img * OUTK + t) * 4 + 3] = b.w;
        out[NIMG * OUTK * 4 + img * OUTK + t] = fil ? 0.0f : scs[gb + e];
        out[NIMG * OUTK * 4 + NIMG * OUTK + img * OUTK + t] = (float)clss[gb + e];
    }
}

extern "C" void kernel_launch(void* const* d_in, const int* in_sizes, int n_in,
                              void* d_out, int out_size, void* d_ws, size_t ws_size,
                              hipStream_t stream) {
    Params P;
    for (int l = 0; l < 5; l++) {
        P.cls[l] = (const float*)d_in[l * 3 + 0];
        P.reg[l] = (const float*)d_in[l * 3 + 1];
        P.anc[l] = (const float*)d_in[l * 3 + 2];
    }
    P.imsize = (const int*)d_in[15];

    char* w = (char*)d_ws;
    uint64_t* rowCand  = (uint64_t*)(w + 0);        // 80*8192*8 = 5,242,880
    float4*   boff     = (float4*)(w + 0);          // 1,280,000 (alias, k_merge->k_out)
    float*    area     = (float*)(w + 1280000);     // 320,000 -> 1,600,000
    float4*   bclipb   = (float4*)(w + 1600000);    // 1,280,000 -> 2,880,000
    float*    scs      = (float*)(w + 2880000);     // 320,000 -> 3,200,000
    int*      clss     = (int*)(w + 3200000);       // 320,000 -> 3,520,000
    int*      sel      = (int*)(w + 5242880);       // 1,280 -> 5,244,160
    float*    T        = (float*)(w + 5244160);     // 1,152 -> 5,245,312
    uint32_t* hist     = (uint32_t*)(w + 5245312);  // 80*288*4 = 92,160 -> 5,337,472
    uint32_t* rowCnt   = (uint32_t*)(w + 5337472);  // 320 -> 5,337,792
    uint32_t* fbflag   = (uint32_t*)(w + 5337792);  // 320 -> 5,338,112
    uint32_t* histBad  = (uint32_t*)(w + 5338112);  // 320 -> 5,338,432
    uint64_t* keys     = (uint64_t*)(w + 5338432);  // 16*5120*8 = 655,360 -> 5,993,792
    uint8_t*  keepB    = (uint8_t*)(w + 5993792);   // 80,000 -> 6,073,792
    uint8_t*  clsB     = (uint8_t*)(w + 6073792);   // 80,000 -> 6,153,792

    k_thr<<<80, 320, 0, stream>>>(T, hist, rowCnt);
    k_hist<<<NCHUNK, 256, 0, stream>>>(P, T, hist, rowCand, rowCnt, fbflag, histBad);
    k_scanfb<<<80, 1024, 0, stream>>>(P, T, hist, sel, fbflag, histBad);
    k_selkr<<<NIMG * NLEV, 1024, 0, stream>>>(P, sel, T, rowCand, rowCnt, fbflag, keys);
    k_merge<<<NIMG * 4, 1024, 0, stream>>>(P, keys, boff, area, bclipb, scs, clss, keepB, clsB);
    k_cnms<<<NIMG * NCLS, 64, 0, stream>>>(boff, area, clsB, keepB);
    k_out<<<NIMG, 64, 0, stream>>>(bclipb, scs, clss, keepB, (float*)d_out);
}

// Round 22
// 162.584 us; speedup vs baseline: 1.0595x; 1.0595x over previous
//
#include <hip/hip_runtime.h>
#include <stdint.h>
#include <math.h>

#define NLEV 5
#define NIMG 16
#define NCLS 80
#define TOPK 1000
#define MTOT 5000
#define LPAD 1024
#define BNDCAP 4096
#define NBINS 288
#define BIN0 7846
#define OUTK 100
#define CHUNK 8192
#define NCHUNK 3216
#define CCAND 1024
#define ROWCAP 8192
#define CCAP 512

__device__ __constant__ int c_HW[NLEV]   = {15200, 3800, 950, 247, 70};
__device__ __constant__ int c_E[NLEV]    = {1216000, 304000, 76000, 19760, 5600};
__device__ __constant__ int c_cpr[NLEV]  = {149, 38, 10, 3, 1};          // 8192-chunks per (img,level) row
__device__ __constant__ int c_cbase[NLEV + 1] = {0, 2384, 2992, 3152, 3200, 3216};
// per-level gather-threshold bin: selection boundary B is ~{269,257,232,173,~60}
// on this data; GB chosen well below with 3x count margin. B < GB[l] -> exact fallback.
__device__ __constant__ int c_GB[NLEV]   = {256, 230, 179, 64, 0};

struct Params {
    const float* cls[NLEV];
    const float* reg[NLEV];
    const float* anc[NLEV];
    const int* imsize;
};

// ---- shared decode (must be used identically by k_selkr and k_merge) ----
__device__ inline void decode_entry(const Params& P, int img, int lvl, uint32_t idx,
                                    float bclip[4], int* cls_out, bool* nonempty) {
    int HW = c_HW[lvl];
    int loc = (int)idx / NCLS;
    int c = (int)idx - loc * NCLS;
    const float* a = P.anc[lvl] + 4 * loc;
    float a0 = a[0], a1 = a[1], a2 = a[2], a3 = a[3];
    const float* rg = P.reg[lvl] + (size_t)img * 4 * HW + loc;
    float d0 = rg[0], d1 = rg[HW], d2 = rg[2 * HW], d3 = rg[3 * HW];
    float w = a2 - a0 + 1.0f, h = a3 - a1 + 1.0f;
    float cx = a0 + 0.5f * w, cy = a1 + 0.5f * h;
    float dx = d0 / 10.0f, dy = d1 / 10.0f;
    const float SCALE_CLAMP = 4.135166556742356f;
    float dw = fminf(d2 / 5.0f, SCALE_CLAMP);
    float dh = fminf(d3 / 5.0f, SCALE_CLAMP);
    float pcx = dx * w + cx, pcy = dy * h + cy;
    float pw = (float)exp((double)dw) * w;
    float ph = (float)exp((double)dh) * h;
    float x1 = pcx - 0.5f * (pw - 1.0f), y1 = pcy - 0.5f * (ph - 1.0f);
    float x2 = pcx + 0.5f * (pw - 1.0f), y2 = pcy + 0.5f * (ph - 1.0f);
    float Hs = (float)P.imsize[img * 2 + 0];
    float Ws = (float)P.imsize[img * 2 + 1];
    float x1c = fminf(fmaxf(x1, 0.0f), Ws);
    float y1c = fminf(fmaxf(y1, 0.0f), Hs);
    float x2c = fminf(fmaxf(x2, 0.0f), Ws);
    float y2c = fminf(fmaxf(y2, 0.0f), Hs);
    bclip[0] = x1c; bclip[1] = y1c; bclip[2] = x2c; bclip[3] = y2c;
    *cls_out = c;
    *nonempty = ((x2c - x1c) > 0.0f) && ((y2c - y1c) > 0.0f);
}

__device__ inline float sigmoid_f(float x) {
    return (float)(1.0 / (1.0 + exp(-(double)x)));
}

__device__ inline uint32_t f2o(float f) {
    uint32_t b = __float_as_uint(f);
    return (b & 0x80000000u) ? ~b : (b | 0x80000000u);
}
__device__ inline float o2f(uint32_t o) {
    uint32_t b = (o & 0x80000000u) ? (o & 0x7FFFFFFFu) : ~o;
    return __uint_as_float(b);
}

__device__ inline void chunk_map(int bid, int* lvl, int* img, int* start, int* end) {
    int l = 0;
#pragma unroll
    for (int q = 1; q < NLEV; q++) if (bid >= c_cbase[q]) l = q;
    int r = bid - c_cbase[l];
    int cpr = c_cpr[l];
    int im = r / cpr;
    int ch = r - im * cpr;
    int E = c_E[l];
    int st = ch * CHUNK;
    *lvl = l; *img = im; *start = st; *end = min(st + CHUNK, E);
}

// ---- K0: thresholds T[b] + zero hist + zero rowCnt/fbflag/histBad ----
__global__ __launch_bounds__(320) void k_thr(float* T, uint32_t* hist, uint32_t* cnts) {
    int b = blockIdx.x;
    int t = threadIdx.x;
    if (t < NBINS) hist[b * NBINS + t] = 0;
    if (b == 1 && t < 240) cnts[t] = 0;     // rowCnt[80] + fbflag[80] + histBad[80]
    if (b == 0 && t < NBINS) {
        uint32_t lo = f2o(-4.0f), hi = f2o(20.0f);
        while (hi - lo > 1u) {
            uint32_t mid = lo + ((hi - lo) >> 1);
            float xm = o2f(mid);
            float s = sigmoid_f(xm);
            bool pass = (s > 0.05f) && (((int)(__float_as_uint(s) >> 17) - BIN0) >= t);
            if (pass) hi = mid; else lo = mid;
        }
        float xr = o2f(hi);
        float sv = sigmoid_f(xr);
        bool ok = (sv > 0.05f) && (((int)(__float_as_uint(sv) >> 17) - BIN0) >= t);
        T[t] = ok ? xr : __uint_as_float(0x7F800000u);
    }
}

// ---- K1: single 104MB stream (best-measured variant: register preload +
// push-only hot loop; bin/idx in compact post-pass). ~51us, ceiling-pinned. ----
__global__ __launch_bounds__(256) void k_hist(Params P, const float* __restrict__ T,
                                              uint32_t* __restrict__ hist,
                                              uint64_t* __restrict__ rowCand,
                                              uint32_t* __restrict__ rowCnt,
                                              uint32_t* __restrict__ fbflag,
                                              uint32_t* __restrict__ histBad) {
    __shared__ uint32_t lh[NBINS];
    __shared__ float sT[NBINS];
    __shared__ uint64_t cand[CCAND];
    __shared__ uint32_t ccnt, wbase;
    int l, img, start, end;
    chunk_map(blockIdx.x, &l, &img, &start, &end);
    for (int b = threadIdx.x; b < NBINS; b += 256) { lh[b] = 0; sT[b] = T[b]; }
    if (threadIdx.x == 0) ccnt = 0;
    __syncthreads();
    float gthr = sT[c_GB[l]];
    int HW = c_HW[l];
    int row = l * NIMG + img;
    const float4* __restrict__ p = (const float4*)(P.cls[l] + (size_t)img * c_E[l] + start);
    int n4 = (end - start) >> 2;
    float4 r[8];
#pragma unroll
    for (int u = 0; u < 8; u++) {
        int f = u * 256 + threadIdx.x;
        r[u] = (f < n4) ? p[f] : make_float4(-1e30f, -1e30f, -1e30f, -1e30f);
    }
    __builtin_amdgcn_sched_barrier(0);
#pragma unroll
    for (int u = 0; u < 8; u++) {
        float4 x4 = r[u];
        float xs[4] = {x4.x, x4.y, x4.z, x4.w};
#pragma unroll
        for (int k = 0; k < 4; k++) {
            float xv = xs[k];
            if (xv >= gthr) {                     // push-only: bits + chunk pos
                uint32_t lp = atomicAdd(&ccnt, 1u);
                if (lp < CCAND) {
                    uint32_t pos = (uint32_t)((u * 256 + threadIdx.x) * 4 + k);
                    cand[lp] = ((uint64_t)__float_as_uint(xv) << 32) | pos;
                }
            }
        }
    }
    __syncthreads();
    uint32_t cc = ccnt;
    uint32_t n = min(cc, (uint32_t)CCAND);
    if (threadIdx.x == 0) {
        wbase = atomicAdd(&rowCnt[row], n);
        if (cc > CCAND) { atomicOr(&fbflag[row], 1u); atomicOr(&histBad[row], 1u); }
        else if (wbase + n > ROWCAP) atomicOr(&fbflag[row], 1u);
    }
    __syncthreads();
    // ---- compact post-pass: exact bin + idx + rowCand write (~94 items) ----
    for (uint32_t i = threadIdx.x; i < n; i += 256) {
        uint64_t rec = cand[i];
        float xv = __uint_as_float((uint32_t)(rec >> 32));
        int pos = (int)(rec & 0xFFFFu);
        float se = 1.0f / (1.0f + __expf(-xv));   // estimator only
        int b = (int)(__float_as_uint(se) >> 17) - BIN0;
        b = min(max(b, 0), NBINS - 1);
        while (b > 0 && xv < sT[b]) b--;          // exact fix-up:
        while (b + 1 < NBINS && xv >= sT[b + 1]) b++;  // T[b]<=x<T[b+1]
        atomicAdd(&lh[b], 1u);
        int q2 = start + pos;                     // c*HW + p layout
        int c = q2 / HW;
        int pidx = q2 - c * HW;
        uint32_t idx = (uint32_t)(pidx * NCLS + c);
        uint32_t gpos = wbase + i;
        if (gpos < ROWCAP)
            rowCand[(size_t)row * ROWCAP + gpos] = ((uint64_t)__float_as_uint(xv) << 32) | idx;
    }
    __syncthreads();
    for (int b = threadIdx.x; b < NBINS; b += 256) {
        uint32_t c = lh[b];
        if (c) atomicAdd(&hist[row * NBINS + b], c);
    }
}

// ---- K2 (fused scan + fallback + selsort + keys + rsort), one dispatch ----
// Scans the row histogram inline (thread 0); on scan failure or untrusted
// hist, recomputes an exact full-range hist from the raw row (dormant) and
// rescans. Then: filter records (logit T-compares, exact), sort boundary
// bin by exact score bits, build & sort the row's 1024 keys, store. ----
__global__ __launch_bounds__(1024) void k_selkr(Params P, const float* T,
                                                const uint32_t* hist,
                                                const uint64_t* rowCand, const uint32_t* rowCnt,
                                                const uint32_t* fbflag, const uint32_t* histBad,
                                                uint64_t* keys) {
    __shared__ uint64_t smain[1024];
    __shared__ uint64_t sbnd[BNDCAP];
    __shared__ uint64_t kk[LPAD];
    __shared__ uint32_t lhist[NBINS];
    __shared__ uint32_t cnt0, cnt1;
    __shared__ int s_B, s_cab, s_need, s_cum, s_fail;
    int blk = blockIdx.x;              // keys layout [img][lvl][1024]
    int img = blk / NLEV, lvl = blk - img * NLEV;
    int row = lvl * NIMG + img;
    int E = c_E[lvl];
    int HW = c_HW[lvl];
    // ---- inline scan (was k_scanfb) ----
    if (threadIdx.x < NBINS) lhist[threadIdx.x] = hist[row * NBINS + threadIdx.x];
    if (threadIdx.x == 0) { cnt0 = 0; cnt1 = 0; s_fail = 0; }
    __syncthreads();
    if (threadIdx.x == 0) {
        int GBl = c_GB[lvl];
        int cum = 0, B = -3, need = 0, cab = 0;
        if (histBad[row] == 0) {
            for (int b = NBINS - 1; b >= GBl; b--) {
                int c = (int)lhist[b];
                if (cum + c >= TOPK) { B = b; cab = cum; need = TOPK - cum; break; }
                cum += c;
            }
        }
        if (B == -3) s_fail = 1;
        else { s_B = B; s_cab = cab; s_need = need; s_cum = cum; }
    }
    __syncthreads();
    if (s_fail) {
        // exact full-range hist recompute (slow path, correctness valve)
        float t0 = T[0];
        for (int b = threadIdx.x; b < NBINS; b += 1024) lhist[b] = 0;
        __syncthreads();
        const float* base = P.cls[lvl] + (size_t)img * E;
        for (int e = threadIdx.x; e < E; e += 1024) {
            float xv = base[e];
            if (xv >= t0) {
                float sc = sigmoid_f(xv);
                int b = (int)(__float_as_uint(sc) >> 17) - BIN0;
                b = min(max(b, 0), NBINS - 1);
                atomicAdd(&lhist[b], 1u);
            }
        }
        __syncthreads();
        if (threadIdx.x == 0) {
            int cum = 0, B = -1, need = 0, cab = 0;
            for (int b = NBINS - 1; b >= 0; b--) {
                int c = (int)lhist[b];
                if (cum + c >= TOPK) { B = b; cab = cum; need = TOPK - cum; break; }
                cum += c;
            }
            if (B < 0) { cab = cum; need = 0; }
            s_B = B; s_cab = cab; s_need = need; s_cum = cum;
        }
        __syncthreads();
    }
    int B = s_B, cab = s_cab, need = s_need, cum = s_cum;
    float xt = T[max(B, 0)];                       // == T[B] when B>=0
    float tB1 = T[min(B + 1, NBINS - 1)];          // bin>B  <=> x >= T[B+1]
    uint32_t rcnt = rowCnt[row];
    bool fb = (fbflag[row] != 0) || (rcnt > ROWCAP) || s_fail;
    if (!fb) {
        const uint64_t* rc = rowCand + (size_t)row * ROWCAP;
        int cntr = (int)rcnt;
        for (int i = threadIdx.x; i < cntr; i += 1024) {
            uint64_t rec = rc[i];
            float x = __uint_as_float((uint32_t)(rec >> 32));
            if (x >= tB1) {
                uint32_t lp = atomicAdd(&cnt0, 1u);
                if (lp < 1024) smain[lp] = rec;   // cab<=999 -> never overflows
            } else if (x >= xt) {
                uint32_t lp = atomicAdd(&cnt1, 1u);
                if (lp < BNDCAP) sbnd[lp] = rec;
            }
        }
    } else {
        // ---- exact fallback: direct full-row scan (slow path) ----
        const float* base = P.cls[lvl] + (size_t)img * E;
        for (int e = threadIdx.x; e < E; e += 1024) {
            float xv = base[e];
            if (xv >= xt) {
                int c = e / HW;
                int pidx = e - c * HW;
                uint32_t idx = (uint32_t)(pidx * NCLS + c);
                uint64_t rec = ((uint64_t)__float_as_uint(xv) << 32) | idx;
                if (xv >= tB1) {
                    uint32_t lp = atomicAdd(&cnt0, 1u);
                    if (lp < 1024) smain[lp] = rec;
                } else {
                    uint32_t lp = atomicAdd(&cnt1, 1u);
                    if (lp < BNDCAP) sbnd[lp] = rec;
                }
            }
        }
    }
    __syncthreads();
    // ---- boundary: convert logit->exact score bits, sort (desc, idx asc) ----
    int take = 0;
    int cnt = min((int)cnt1, BNDCAP);
    if (need > 0) {
        for (int i = threadIdx.x; i < cnt; i += 1024) {
            uint64_t r = sbnd[i];
            float x = __uint_as_float((uint32_t)(r >> 32));
            uint32_t sb = __float_as_uint(sigmoid_f(x));
            sbnd[i] = ((uint64_t)(uint32_t)(~sb) << 32) | (uint32_t)r;
        }
        __syncthreads();
        int N = 64; while (N < cnt) N <<= 1;
        for (int i = threadIdx.x; i < N; i += 1024) {
            if (i >= cnt) sbnd[i] = ~0ULL;
        }
        __syncthreads();
        for (int k = 2; k <= N; k <<= 1) {
            for (int j = k >> 1; j > 0; j >>= 1) {
                for (int i = threadIdx.x; i < N; i += 1024) {
                    int ixj = i ^ j;
                    if (ixj > i) {
                        uint64_t A = sbnd[i], Bv = sbnd[ixj];
                        bool up = ((i & k) == 0);
                        if (up ? (A > Bv) : (A < Bv)) { sbnd[i] = Bv; sbnd[ixj] = A; }
                    }
                }
                __syncthreads();
            }
        }
        take = min(need, cnt);
    }
    int nmain = min((int)cnt0, 1024);
    int filled = (B < 0) ? cum : (cab + take);
    // ---- build 1024 keys (exact score bits via sigmoid_f), sort, store ----
    for (int slot = threadIdx.x; slot < LPAD; slot += 1024) {
        uint64_t key;
        if (slot >= TOPK) key = ~0ULL;
        else {
            uint32_t bits = 0, idx = 0;
            if (slot < filled) {
                if (slot < cab || B < 0) {
                    if (slot < nmain) {
                        uint64_t r = smain[slot];
                        float x = __uint_as_float((uint32_t)(r >> 32));
                        bits = __float_as_uint(sigmoid_f(x));
                        idx = (uint32_t)r;
                    }
                } else {
                    uint64_t wv = sbnd[slot - cab];
                    bits = ~((uint32_t)(wv >> 32));
                    idx = (uint32_t)wv;
                }
            }
            uint32_t be = 0;
            if (bits != 0) {
                float bc[4]; int cc; bool ne;
                decode_entry(P, img, lvl, idx, bc, &cc, &ne);
                if (ne) be = bits;
            }
            key = ((uint64_t)(uint32_t)(~be) << 24) | ((uint64_t)lvl << 21) | (uint64_t)idx;
        }
        kk[slot] = key;
    }
    __syncthreads();
    for (int k = 2; k <= LPAD; k <<= 1) {
        for (int j = k >> 1; j > 0; j >>= 1) {
            for (int i = threadIdx.x; i < LPAD; i += 1024) {
                int ixj = i ^ j;
                if (ixj > i) {
                    uint64_t A = kk[i], Bv = kk[ixj];
                    bool up = ((i & k) == 0);
                    if (up ? (A > Bv) : (A < Bv)) { kk[i] = Bv; kk[ixj] = A; }
                }
            }
            __syncthreads();
        }
    }
    uint64_t* g = keys + (size_t)blk * LPAD;
    for (int i = threadIdx.x; i < LPAD; i += 1024) g[i] = kk[i];
}

// ---- K3 (fused merge+prep): 4 blocks/image ----
__global__ __launch_bounds__(1024) void k_merge(Params P, const uint64_t* keys,
                                                float4* boff, float* area, float4* bclip,
                                                float* scs, int* clss,
                                                uint8_t* keepB, uint8_t* clsB) {
    __shared__ uint64_t sl[NLEV * LPAD];   // 40 KB
    int img = blockIdx.x >> 2;
    int part = blockIdx.x & 3;
    const uint64_t* g = keys + (size_t)img * NLEV * LPAD;
    for (int i = threadIdx.x; i < NLEV * LPAD; i += 1024) sl[i] = g[i];
    __syncthreads();
    const int gb = img * MTOT;
    int e0 = part * (NLEV * LPAD / 4);
    int e1 = e0 + (NLEV * LPAD / 4);
    for (int e = e0 + threadIdx.x; e < e1; e += 1024) {
        int l = e >> 10, i = e & (LPAD - 1);
        if (i >= TOPK) continue;
        uint64_t K = sl[e];
        int rank = i;
#pragma unroll
        for (int l2 = 0; l2 < NLEV; l2++) {
            if (l2 == l) continue;
            const uint64_t* s2 = &sl[l2 << 10];
            int lo = 0, hi = TOPK;
            while (lo < hi) {
                int mid = (lo + hi) >> 1;
                if (s2[mid] < K) lo = mid + 1; else hi = mid;
            }
            rank += lo;
        }
        uint32_t bits = ~((uint32_t)(K >> 24));
        int lvl = (int)((K >> 21) & 7);
        uint32_t idx = (uint32_t)(K & 0x1FFFFF);
        float bc[4]; int cc; bool ne;
        decode_entry(P, img, lvl, idx, bc, &cc, &ne);
        float sc = 0.0f;
        if (bits != 0) {
            float s = __uint_as_float(bits);
            sc = sqrtf(fmaxf(s, 1e-12f));
        }
        float off = (float)cc * 2000.0f;
        float b0 = bc[0] + off, b1 = bc[1] + off, b2 = bc[2] + off, b3 = bc[3] + off;
        int t = gb + rank;
        boff[t] = make_float4(b0, b1, b2, b3);
        area[t] = (b2 - b0) * (b3 - b1);
        bclip[t] = make_float4(bc[0], bc[1], bc[2], bc[3]);
        scs[t] = sc;
        clss[t] = cc;
        keepB[t] = 0;
        clsB[t] = (sc != 0.0f) ? (uint8_t)cc : (uint8_t)0xFF;
    }
}

// ---- K4: per-(img,class) greedy NMS; byte-map bucket build ----
__global__ __launch_bounds__(64) void k_cnms(const float4* boff, const float* area,
                                             const uint8_t* clsB, uint8_t* keepB) {
    __shared__ float sx1[CCAP], sy1[CCAP], sx2[CCAP], sy2[CCAP], sar[CCAP];
    __shared__ uint16_t ranks[CCAP];
    int img = blockIdx.x / NCLS;
    int cls = blockIdx.x - img * NCLS;
    int lane = threadIdx.x;
    const int gb = img * MTOT;

    int n = 0;
    const uchar4* cp = (const uchar4*)(clsB + gb);
    for (int base = 0; base < 1250; base += 64) {
        int q = base + lane;
        uchar4 cv = (q < 1250) ? cp[q] : make_uchar4(255, 255, 255, 255);
#pragma unroll
        for (int b = 0; b < 4; b++) {
            int cb = (b == 0) ? cv.x : (b == 1) ? cv.y : (b == 2) ? cv.z : cv.w;
            bool pred = (cb == cls);
            uint64_t mask = __ballot(pred);
            int pos = n + (int)__popcll(mask & ((1ULL << lane) - 1ULL));
            if (pred && pos < CCAP) ranks[pos] = (uint16_t)(q * 4 + b);
            n += (int)__popcll(mask);
        }
    }
    n = min(n, CCAP);
    __syncthreads();
    if (n == 0) return;

    for (int i = lane; i < n; i += 64) {
        int t = ranks[i];
        float4 b = boff[gb + t];
        sx1[i] = b.x; sy1[i] = b.y; sx2[i] = b.z; sy2[i] = b.w;
        sar[i] = area[gb + t];
    }
    __syncthreads();

    uint64_t m[CCAP / 64];
#pragma unroll
    for (int c = 0; c < CCAP / 64; c++) m[c] = 0ULL;
#pragma unroll
    for (int c = 0; c < CCAP / 64; c++) {
        if (c * 64 >= n) break;
        for (int ii = 0; ii < 64; ii++) {
            int i = c * 64 + ii;
            if (i >= n) break;
            if ((m[c] >> ii) & 1ULL) continue;
            float bx1 = sx1[i], by1 = sy1[i], bx2 = sx2[i], by2 = sy2[i], bai = sar[i];
            if (lane == 0) keepB[gb + ranks[i]] = 1;
#pragma unroll
            for (int c2 = 0; c2 < CCAP / 64; c2++) {
                if (c2 < c) continue;
                if (c2 * 64 >= n) break;
                int j = c2 * 64 + lane;
                float xx1 = fmaxf(bx1, sx1[j]), yy1 = fmaxf(by1, sy1[j]);
                float xx2 = fminf(bx2, sx2[j]), yy2 = fminf(by2, sy2[j]);
                float inter = fmaxf(xx2 - xx1, 0.0f) * fmaxf(yy2 - yy1, 0.0f);
                float iou = inter / (bai + sar[j] - inter + 1e-9f);
                bool pr = (j > i) && (j < n) && (iou > 0.6f);
                m[c2] |= __ballot(pr);
            }
        }
    }
}

// ---- K5: per-image output: first 100 kept (rank order) + filler ----
__global__ __launch_bounds__(64) void k_out(const float4* bclip, const float* scs,
                                            const int* clss, const uint8_t* keepB, float* out) {
    __shared__ int keptIdx[OUTK];
    int img = blockIdx.x;
    int lane = threadIdx.x;
    const int gb = img * MTOT;
    int kc = 0;
    for (int base = 0; base < MTOT && kc < OUTK; base += 64) {
        int t = base + lane;
        bool pred = (t < MTOT) && (keepB[gb + t] != 0);
        uint64_t mask = __ballot(pred);
        int pos = kc + (int)__popcll(mask & ((1ULL << lane) - 1ULL));
        if (pred && pos < OUTK) keptIdx[pos] = t;
        kc = min(kc + (int)__popcll(mask), OUTK);
    }
    for (int base = 0; base < MTOT && kc < OUTK; base += 64) {
        int t = base + lane;
        bool pred = (t < MTOT) && (keepB[gb + t] == 0);
        uint64_t mask = __ballot(pred);
        int pos = kc + (int)__popcll(mask & ((1ULL << lane) - 1ULL));
        if (pred && pos < OUTK) keptIdx[pos] = t | (1 << 30);
        kc = min(kc + (int)__popcll(mask), OUTK);
    }
    __syncthreads();
    for (int t = lane; t < OUTK; t += 64) {
        int ke = keptIdx[t];
        bool fil = (ke >> 30) & 1;
        int e = ke & 0x3FFFFFFF;
        float4 b = bclip[gb + e];
        out[((size_t)img * OUTK + t) * 4 + 0] = b.x;
        out[((size_t)img * OUTK + t) * 4 + 1] = b.y;
        out[((size_t)img * OUTK + t) * 4 + 2] = b.z;
        out[((size_t)img * OUTK + t) * 4 + 3] = b.w;
        out[NIMG * OUTK * 4 + img * OUTK + t] = fil ? 0.0f : scs[gb + e];
        out[NIMG * OUTK * 4 + NIMG * OUTK + img * OUTK + t] = (float)clss[gb + e];
    }
}

extern "C" void kernel_launch(void* const* d_in, const int* in_sizes, int n_in,
                              void* d_out, int out_size, void* d_ws, size_t ws_size,
                              hipStream_t stream) {
    Params P;
    for (int l = 0; l < 5; l++) {
        P.cls[l] = (const float*)d_in[l * 3 + 0];
        P.reg[l] = (const float*)d_in[l * 3 + 1];
        P.anc[l] = (const float*)d_in[l * 3 + 2];
    }
    P.imsize = (const int*)d_in[15];

    char* w = (char*)d_ws;
    uint64_t* rowCand  = (uint64_t*)(w + 0);        // 80*8192*8 = 5,242,880
    float4*   boff     = (float4*)(w + 0);          // 1,280,000 (alias, k_merge->k_out)
    float*    area     = (float*)(w + 1280000);     // 320,000 -> 1,600,000
    float4*   bclipb   = (float4*)(w + 1600000);    // 1,280,000 -> 2,880,000
    float*    scs      = (float*)(w + 2880000);     // 320,000 -> 3,200,000
    int*      clss     = (int*)(w + 3200000);       // 320,000 -> 3,520,000
    float*    T        = (float*)(w + 5242880);     // 1,152 -> 5,244,032
    uint32_t* hist     = (uint32_t*)(w + 5244032);  // 80*288*4 = 92,160 -> 5,336,192
    uint32_t* rowCnt   = (uint32_t*)(w + 5336192);  // 320 -> 5,336,512
    uint32_t* fbflag   = (uint32_t*)(w + 5336512);  // 320 -> 5,336,832
    uint32_t* histBad  = (uint32_t*)(w + 5336832);  // 320 -> 5,337,152
    uint64_t* keys     = (uint64_t*)(w + 5337152);  // 16*5120*8 = 655,360 -> 5,992,512
    uint8_t*  keepB    = (uint8_t*)(w + 5992512);   // 80,000 -> 6,072,512
    uint8_t*  clsB     = (uint8_t*)(w + 6072512);   // 80,000 -> 6,152,512

    k_thr<<<80, 320, 0, stream>>>(T, hist, rowCnt);
    k_hist<<<NCHUNK, 256, 0, stream>>>(P, T, hist, rowCand, rowCnt, fbflag, histBad);
    k_selkr<<<NIMG * NLEV, 1024, 0, stream>>>(P, T, hist, rowCand, rowCnt, fbflag, histBad, keys);
    k_merge<<<NIMG * 4, 1024, 0, stream>>>(P, keys, boff, area, bclipb, scs, clss, keepB, clsB);
    k_cnms<<<NIMG * NCLS, 64, 0, stream>>>(boff, area, clsB, keepB);
    k_out<<<NIMG, 64, 0, stream>>>(bclipb, scs, clss, keepB, (float*)d_out);
}